// Round 1
// baseline (951.873 us; speedup 1.0000x reference)
//
#include <hip/hip_runtime.h>

#define NN 10000
#define BB 32
#define EE 40000
#define HH 4
#define DD 10
#define TT 10
#define NEG 0.2f

#define NB   (NN*BB)          // 320000
#define NBT  (NN*BB*TT)       // 3200000
#define NBH  (NN*BB*HH)       // 1280000
#define NBHD (NN*BB*HH*DD)    // 12800000

// ---------------- extract mu/sigma + regression heads ----------------
__global__ void extract_kernel(const float* __restrict__ x,
                               const float* __restrict__ wmu, const float* __restrict__ bmu,
                               const float* __restrict__ wsg, const float* __restrict__ bsg,
                               float* __restrict__ mu, float* __restrict__ sg,
                               float* __restrict__ regmu, float* __restrict__ regsg) {
    int i = blockIdx.x * blockDim.x + threadIdx.x;   // over N*B
    if (i >= NB) return;
    int n = i / BB, b = i % BB;
    float smu = 0.f, ssg = 0.f;
    float muv[TT], sgv[TT];
#pragma unroll
    for (int t = 0; t < TT; t++) {
        size_t xi = (((size_t)t * NN + n) * BB + b) * 3;
        float m = x[xi], s = x[xi + 1];
        muv[t] = m; sgv[t] = s;
        smu += m * wmu[t];
        ssg += s * wsg[t];
    }
#pragma unroll
    for (int t = 0; t < TT; t++) {
        mu[(size_t)i * TT + t] = muv[t];
        sg[(size_t)i * TT + t] = sgv[t];
    }
    regmu[i] = smu + bmu[0];
    regsg[i] = ssg + bsg[0];
}

// ---------------- CSR build ----------------
__global__ void deg_kernel(const int* __restrict__ dst, int* __restrict__ deg) {
    int e = blockIdx.x * blockDim.x + threadIdx.x;
    if (e < EE) atomicAdd(&deg[dst[e]], 1);
}

__global__ void scan_kernel(const int* __restrict__ deg, int* __restrict__ off) {
    __shared__ int sm[1024];
    __shared__ int carry_s;
    if (threadIdx.x == 0) { carry_s = 0; off[0] = 0; }
    __syncthreads();
    for (int base = 0; base < NN; base += 1024) {
        int i = base + (int)threadIdx.x;
        int v = (i < NN) ? deg[i] : 0;
        sm[threadIdx.x] = v;
        __syncthreads();
        for (int s = 1; s < 1024; s <<= 1) {
            int t = (threadIdx.x >= (unsigned)s) ? sm[threadIdx.x - s] : 0;
            __syncthreads();
            sm[threadIdx.x] += t;
            __syncthreads();
        }
        if (i < NN) off[i + 1] = carry_s + sm[threadIdx.x];
        __syncthreads();
        if (threadIdx.x == 0) carry_s += sm[1023];
        __syncthreads();
    }
}

__global__ void fill_kernel(const int* __restrict__ src, const int* __restrict__ dst,
                            const int* __restrict__ off, int* __restrict__ cursor,
                            int* __restrict__ csr_src) {
    int e = blockIdx.x * blockDim.x + threadIdx.x;
    if (e < EE) {
        int d = dst[e];
        int p = atomicAdd(&cursor[d], 1);
        csr_src[off[d] + p] = src[e];
    }
}

// ---------------- GAT dense part: ft, el, er ----------------
__global__ void ft_kernel(const float* __restrict__ feat,
                          const float* __restrict__ fcw,   // (H*D, T)
                          const float* __restrict__ al,    // (H,D) flat
                          const float* __restrict__ ar,
                          float* __restrict__ ft, float* __restrict__ el,
                          float* __restrict__ er) {
    __shared__ float sw[HH * DD * TT];
    __shared__ float sal[HH * DD], sar[HH * DD];
    for (int k = threadIdx.x; k < HH * DD * TT; k += blockDim.x) sw[k] = fcw[k];
    for (int k = threadIdx.x; k < HH * DD; k += blockDim.x) { sal[k] = al[k]; sar[k] = ar[k]; }
    __syncthreads();
    int i = blockIdx.x * blockDim.x + threadIdx.x;
    if (i >= NB) return;
    float f[TT];
    const float* fp = feat + (size_t)i * TT;
#pragma unroll
    for (int t = 0; t < TT; t++) f[t] = fp[t];
    float elh[HH] = {0, 0, 0, 0}, erh[HH] = {0, 0, 0, 0};
    float* ftp = ft + (size_t)i * (HH * DD);
#pragma unroll
    for (int o = 0; o < HH * DD; o++) {
        float v = 0.f;
#pragma unroll
        for (int t = 0; t < TT; t++) v += f[t] * sw[o * TT + t];
        ftp[o] = v;
        elh[o / DD] += v * sal[o];
        erh[o / DD] += v * sar[o];
    }
#pragma unroll
    for (int h = 0; h < HH; h++) {
        el[(size_t)i * HH + h] = elh[h];
        er[(size_t)i * HH + h] = erh[h];
    }
}

// ---------------- GAT aggregate: edge softmax + weighted sum + mean over H ----
template <bool STATS>
__global__ void agg_kernel(const float* __restrict__ ft, const float* __restrict__ el,
                           const float* __restrict__ er, const int* __restrict__ off,
                           const int* __restrict__ csr_src,
                           float* __restrict__ g, float* __restrict__ stats) {
    int i = blockIdx.x * blockDim.x + threadIdx.x;
    float lsum = 0.f, lsq = 0.f;
    if (i < NB) {
        int n = i / BB, b = i % BB;
        int s0 = off[n], s1 = off[n + 1];
        float erd[HH];
#pragma unroll
        for (int h = 0; h < HH; h++) erd[h] = er[(size_t)i * HH + h];
        float denom[HH] = {0, 0, 0, 0};
        float acc[HH][DD];
#pragma unroll
        for (int h = 0; h < HH; h++)
#pragma unroll
            for (int d = 0; d < DD; d++) acc[h][d] = 0.f;
        for (int k = s0; k < s1; k++) {
            int s = csr_src[k];
            size_t sb = (size_t)s * BB + b;
            const float* elp = el + sb * HH;
            const float* ftp = ft + sb * (HH * DD);
#pragma unroll
            for (int h = 0; h < HH; h++) {
                float z = elp[h] + erd[h];
                z = (z >= 0.f) ? z : NEG * z;
                float w = __expf(z);
                denom[h] += w;
#pragma unroll
                for (int d = 0; d < DD; d++) acc[h][d] += ftp[h * DD + d] * w;
            }
        }
        float outd[DD];
#pragma unroll
        for (int d = 0; d < DD; d++) outd[d] = 0.f;
#pragma unroll
        for (int h = 0; h < HH; h++) {
            float rd = (s1 > s0) ? (1.0f / denom[h]) : 0.f;
#pragma unroll
            for (int d = 0; d < DD; d++) {
                float v = acc[h][d] * rd;
                v = (v >= 0.f) ? v : NEG * v;
                outd[d] += v;
            }
        }
        float* gp = g + (size_t)i * DD;
#pragma unroll
        for (int d = 0; d < DD; d++) {
            float o = outd[d] * 0.25f;
            gp[d] = o;
            if (STATS) { lsum += o; lsq += o * o; }
        }
    }
    if (STATS) {
#pragma unroll
        for (int o = 32; o > 0; o >>= 1) {
            lsum += __shfl_down(lsum, o, 64);
            lsq  += __shfl_down(lsq, o, 64);
        }
        __shared__ float ssum[4], ssq[4];
        int wid = threadIdx.x >> 6, lid = threadIdx.x & 63;
        if (lid == 0) { ssum[wid] = lsum; ssq[wid] = lsq; }
        __syncthreads();
        if (threadIdx.x == 0) {
            float a = 0.f, q = 0.f;
#pragma unroll
            for (int w = 0; w < 4; w++) { a += ssum[w]; q += ssq[w]; }
            atomicAdd(&stats[0], a);
            atomicAdd(&stats[1], q);
        }
    }
}

// ---------------- LN(A), LN(B), average ----------------
__global__ void lncomb_kernel(const float* __restrict__ ga, const float* __restrict__ gb,
                              const float* __restrict__ stats, float* __restrict__ h) {
    int i = blockIdx.x * blockDim.x + threadIdx.x;
    if (i >= NBT) return;
    const float M = (float)NBT;
    float ma = stats[0] / M; float va = stats[1] / M - ma * ma;
    float mb = stats[2] / M; float vb = stats[3] / M - mb * mb;
    float ra = rsqrtf(va + 1e-5f), rb = rsqrtf(vb + 1e-5f);
    h[i] = 0.5f * ((ga[i] - ma) * ra + (gb[i] - mb) * rb);
}

// ---------------- final combine ----------------
__global__ void outcomb_kernel(const float* __restrict__ reg, const float* __restrict__ ga,
                               const float* __restrict__ gb, float* __restrict__ out) {
    int i = blockIdx.x * blockDim.x + threadIdx.x;
    if (i >= NBT) return;
    int nb = i / DD;
    out[i] = (reg[nb] + ga[i] + gb[i]) * (1.0f / 3.0f);
}

extern "C" void kernel_launch(void* const* d_in, const int* in_sizes, int n_in,
                              void* d_out, int out_size, void* d_ws, size_t ws_size,
                              hipStream_t stream) {
    const float* x      = (const float*)d_in[0];
    const int* ps_src   = (const int*)d_in[1];
    const int* ps_dst   = (const int*)d_in[2];
    const int* rl_src   = (const int*)d_in[3];
    const int* rl_dst   = (const int*)d_in[4];
    const float* mu_p_fc = (const float*)d_in[5];
    const float* mu_p_al = (const float*)d_in[6];
    const float* mu_p_ar = (const float*)d_in[7];
    const float* sg_p_fc = (const float*)d_in[8];
    const float* sg_p_al = (const float*)d_in[9];
    const float* sg_p_ar = (const float*)d_in[10];
    const float* mu_r_fc = (const float*)d_in[11];
    const float* mu_r_al = (const float*)d_in[12];
    const float* mu_r_ar = (const float*)d_in[13];
    const float* sg_r_fc = (const float*)d_in[14];
    const float* sg_r_al = (const float*)d_in[15];
    const float* sg_r_ar = (const float*)d_in[16];
    const float* reg_mu_w = (const float*)d_in[17];
    const float* reg_mu_b = (const float*)d_in[18];
    const float* reg_sg_w = (const float*)d_in[19];
    const float* reg_sg_b = (const float*)d_in[20];

    float* out = (float*)d_out;

    // ---- workspace carve ----
    float* fw = (float*)d_ws;
    float* mu    = fw;              fw += NBT;
    float* sigma = fw;              fw += NBT;
    float* gA    = fw;              fw += NBT;
    float* gB    = fw;              fw += NBT;
    float* hp    = fw;              fw += NBT;
    float* hrl   = fw;              fw += NBT;
    float* regmu = fw;              fw += NB;
    float* regsg = fw;              fw += NB;
    float* el    = fw;              fw += NBH;
    float* er    = fw;              fw += NBH;
    float* ft    = fw;              fw += NBHD;
    int* iw = (int*)fw;
    int* ps_off = iw;               iw += NN + 1;
    int* rl_off = iw;               iw += NN + 1;
    int* ps_csr = iw;               iw += EE;
    int* rl_csr = iw;               iw += EE;
    // zero region starts here:
    int* deg_ps = iw;               iw += NN;
    int* cur_ps = iw;               iw += NN;
    int* deg_rl = iw;               iw += NN;
    int* cur_rl = iw;               iw += NN;
    float* stats = (float*)iw;      // 8 floats
    size_t zero_bytes = (size_t)(4 * NN) * sizeof(int) + 8 * sizeof(float);
    hipMemsetAsync(deg_ps, 0, zero_bytes, stream);

    const int TPB = 256;
    const int GRID_NB  = (NB + TPB - 1) / TPB;
    const int GRID_NBT = (NBT + TPB - 1) / TPB;
    const int GRID_E   = (EE + TPB - 1) / TPB;

    extract_kernel<<<GRID_NB, TPB, 0, stream>>>(x, reg_mu_w, reg_mu_b, reg_sg_w, reg_sg_b,
                                                mu, sigma, regmu, regsg);

    // CSR for both graphs
    deg_kernel<<<GRID_E, TPB, 0, stream>>>(ps_dst, deg_ps);
    deg_kernel<<<GRID_E, TPB, 0, stream>>>(rl_dst, deg_rl);
    scan_kernel<<<1, 1024, 0, stream>>>(deg_ps, ps_off);
    scan_kernel<<<1, 1024, 0, stream>>>(deg_rl, rl_off);
    fill_kernel<<<GRID_E, TPB, 0, stream>>>(ps_src, ps_dst, ps_off, cur_ps, ps_csr);
    fill_kernel<<<GRID_E, TPB, 0, stream>>>(rl_src, rl_dst, rl_off, cur_rl, rl_csr);

    // ---- layer-0: pseudo graph ----
    ft_kernel<<<GRID_NB, TPB, 0, stream>>>(mu, mu_p_fc, mu_p_al, mu_p_ar, ft, el, er);
    agg_kernel<true><<<GRID_NB, TPB, 0, stream>>>(ft, el, er, ps_off, ps_csr, gA, stats + 0);
    ft_kernel<<<GRID_NB, TPB, 0, stream>>>(sigma, sg_p_fc, sg_p_al, sg_p_ar, ft, el, er);
    agg_kernel<true><<<GRID_NB, TPB, 0, stream>>>(ft, el, er, ps_off, ps_csr, gB, stats + 2);
    lncomb_kernel<<<GRID_NBT, TPB, 0, stream>>>(gA, gB, stats + 0, hp);

    // ---- layer-0: real graph ----
    ft_kernel<<<GRID_NB, TPB, 0, stream>>>(mu, mu_r_fc, mu_r_al, mu_r_ar, ft, el, er);
    agg_kernel<true><<<GRID_NB, TPB, 0, stream>>>(ft, el, er, rl_off, rl_csr, gA, stats + 4);
    ft_kernel<<<GRID_NB, TPB, 0, stream>>>(sigma, sg_r_fc, sg_r_al, sg_r_ar, ft, el, er);
    agg_kernel<true><<<GRID_NB, TPB, 0, stream>>>(ft, el, er, rl_off, rl_csr, gB, stats + 6);
    lncomb_kernel<<<GRID_NBT, TPB, 0, stream>>>(gA, gB, stats + 4, hrl);

    // ---- final GATs: mu outputs ----
    ft_kernel<<<GRID_NB, TPB, 0, stream>>>(hp, mu_p_fc + 400, mu_p_al + 40, mu_p_ar + 40, ft, el, er);
    agg_kernel<false><<<GRID_NB, TPB, 0, stream>>>(ft, el, er, ps_off, ps_csr, gA, nullptr);
    ft_kernel<<<GRID_NB, TPB, 0, stream>>>(hrl, mu_r_fc + 400, mu_r_al + 40, mu_r_ar + 40, ft, el, er);
    agg_kernel<false><<<GRID_NB, TPB, 0, stream>>>(ft, el, er, rl_off, rl_csr, gB, nullptr);
    outcomb_kernel<<<GRID_NBT, TPB, 0, stream>>>(regmu, gA, gB, out);

    // ---- final GATs: sigma outputs ----
    ft_kernel<<<GRID_NB, TPB, 0, stream>>>(hp, sg_p_fc + 400, sg_p_al + 40, sg_p_ar + 40, ft, el, er);
    agg_kernel<false><<<GRID_NB, TPB, 0, stream>>>(ft, el, er, ps_off, ps_csr, gA, nullptr);
    ft_kernel<<<GRID_NB, TPB, 0, stream>>>(hrl, sg_r_fc + 400, sg_r_al + 40, sg_r_ar + 40, ft, el, er);
    agg_kernel<false><<<GRID_NB, TPB, 0, stream>>>(ft, el, er, rl_off, rl_csr, gB, nullptr);
    outcomb_kernel<<<GRID_NBT, TPB, 0, stream>>>(regsg, gA, gB, out + NBT);
}